// Round 5
// baseline (237.438 us; speedup 1.0000x reference)
//
#include <hip/hip_runtime.h>

#define BB 64
#define CC 128
#define TT 4096
#define NN 6            // KNOT + 2
#define HH 819.0f       // (T-1)/(KNOT+1) = 4095/5, exact in fp32
#define NTHR 512
#define EPT 8           // curve elements per thread per row (NTHR*EPT == TT)
#define NWAVE (NTHR / 64)
#define NROW (BB * CC)
#define NSPAN 5
#define TABBYTES ((size_t)NROW * NSPAN * 16)
#define PADSZ (TT + TT / 32)

typedef float f4 __attribute__((ext_vector_type(4)));

__device__ __forceinline__ void nt_store4(float* p, f4 v) {
    __builtin_nontemporal_store(v, (f4*)p);
}

// LDS pad: +1 float per 32 breaks power-of-2 stride conflicts.
__device__ __forceinline__ int padi(int j) { return j + (j >> 5); }

// ---- 6x6 not-a-knot solve; A compile-time constant -> multipliers fold ----
__device__ __forceinline__ void spline_solve(const float* __restrict__ yy,
                                             int b, int c, float* y, float* Mv)
{
    #pragma unroll
    for (int k = 0; k < NN; ++k)
        y[k] = yy[((size_t)b * NN + k) * CC + c];
    float Aug[NN][NN + 1];
    #pragma unroll
    for (int i = 0; i < NN; ++i)
        #pragma unroll
        for (int j = 0; j < NN + 1; ++j)
            Aug[i][j] = 0.0f;
    Aug[0][0] = 1.0f;  Aug[0][1] = -2.0f;  Aug[0][2] = 1.0f;
    Aug[5][3] = 1.0f;  Aug[5][4] = -2.0f;  Aug[5][5] = 1.0f;
    #pragma unroll
    for (int i = 1; i < NN - 1; ++i) {
        Aug[i][i - 1] = HH / 6.0f;
        Aug[i][i]     = 2.0f * HH / 3.0f;
        Aug[i][i + 1] = HH / 6.0f;
        Aug[i][NN]    = (y[i + 1] - 2.0f * y[i] + y[i - 1]) / HH;
    }
    #pragma unroll
    for (int k = 0; k < NN; ++k) {
        float inv = 1.0f / Aug[k][k];
        #pragma unroll
        for (int i = k + 1; i < NN; ++i) {
            float m = Aug[i][k] * inv;
            #pragma unroll
            for (int j = k; j < NN + 1; ++j)
                Aug[i][j] -= m * Aug[k][j];
        }
    }
    #pragma unroll
    for (int i = NN - 1; i >= 0; --i) {
        float s = Aug[i][NN];
        #pragma unroll
        for (int j = i + 1; j < NN; ++j)
            s -= Aug[i][j] * Mv[j];
        Mv[i] = s / Aug[i][i];
    }
}

__device__ __forceinline__ void horner_coefs(const float* y, const float* Mv,
                                             f4* out5)
{
    const float invh  = 1.0f / HH;
    const float inv6h = 1.0f / (6.0f * HH);
    #pragma unroll
    for (int s = 0; s < NSPAN; ++s) {
        f4 cf;
        cf.x = y[s];
        cf.y = (y[s + 1] - y[s]) * invh - Mv[s] * (HH / 3.0f) - Mv[s + 1] * (HH / 6.0f);
        cf.z = Mv[s] * 0.5f;
        cf.w = (Mv[s + 1] - Mv[s]) * inv6h;
        out5[s] = cf;
    }
}

// ---- setup: per-(row, span) Horner coeffs (a,b,c,d) into workspace ----
__global__ __launch_bounds__(256) void spline_coef_kernel(
    const float* __restrict__ yy, f4* __restrict__ tab)
{
    const int row = blockIdx.x * 256 + threadIdx.x;   // 8192 rows, coalesced in c
    const int b = row / CC;
    const int c = row % CC;
    float y[NN], Mv[NN];
    spline_solve(yy, b, c, y, Mv);
    f4 cf[NSPAN];
    horner_coefs(y, Mv, cf);
    #pragma unroll
    for (int s = 0; s < NSPAN; ++s)
        tab[row * NSPAN + s] = cf[s];
}

// ============================ main kernel ==================================
// 2 rows per block (same b -> same mask). TABLE=1: coeffs from workspace.
template <int TABLE>
__global__ __launch_bounds__(NTHR) void timewarp_kernel(
    const float* __restrict__ x,
    const float* __restrict__ yy,
    const float* __restrict__ mask_rand,
    const f4* __restrict__ tab,
    float* __restrict__ out)
{
    const int r0  = 2 * blockIdx.x;
    const int r1  = r0 + 1;
    const int b   = r0 / CC;           // r0 even -> r0,r1 share b (CC even)
    const int tid = threadIdx.x;

    const float* xr0 = x + (size_t)r0 * TT;
    const float* xr1 = x + (size_t)r1 * TT;
    float* or0       = out + (size_t)r0 * TT;
    float* or1       = out + (size_t)r1 * TT;

    // mask_rand >= 0.5 -> bit-exact copy (uniform per block)
    if (!(mask_rand[b] < 0.5f)) {
        const f4* xi0 = (const f4*)xr0;
        const f4* xi1 = (const f4*)xr1;
        nt_store4(or0 + 4 * tid,          xi0[tid]);
        nt_store4(or0 + 4 * (tid + NTHR), xi0[tid + NTHR]);
        nt_store4(or1 + 4 * tid,          xi1[tid]);
        nt_store4(or1 + 4 * (tid + NTHR), xi1[tid + NTHR]);
        return;
    }

    __shared__ float sh_res0[PADSZ];   // padded scatter targets
    __shared__ float sh_res1[PADSZ];
    __shared__ float sh_w0[NWAVE];     // per-wave scan totals
    __shared__ float sh_w1[NWAVE];

    // ---- span geometry (row-independent) ----
    const int t0 = tid * EPT;
    int idxA = t0 / 819;  if (idxA > 4) idxA = 4;
    int idxB = idxA + 1;  if (idxB > 4) idxB = 4;
    const float xlA = (float)idxA * HH;
    const float xlB = (float)idxB * HH;
    const float tb  = (float)((idxA + 1) * 819);   // first t belonging to span B

    // ---- all global loads issued up front ----
    const f4 a00 = *(const f4*)(xr0 + t0);
    const f4 a01 = *(const f4*)(xr0 + t0 + 4);
    const f4 a10 = *(const f4*)(xr1 + t0);
    const f4 a11 = *(const f4*)(xr1 + t0 + 4);
    const int nb8 = (t0 + EPT < TT) ? (t0 + EPT) : (TT - 1);
    const float fpb0 = xr0[nb8];       // neighbor's first fp, bit-identical bits
    const float fpb1 = xr1[nb8];

    f4 cf0A, cf0B, cf1A, cf1B;
    if (TABLE) {
        cf0A = tab[r0 * NSPAN + idxA];  cf0B = tab[r0 * NSPAN + idxB];
        cf1A = tab[r1 * NSPAN + idxA];  cf1B = tab[r1 * NSPAN + idxB];
    } else {
        float y[NN], Mv[NN];
        f4 cf[NSPAN];
        spline_solve(yy, b, r0 % CC, y, Mv);
        horner_coefs(y, Mv, cf);
        cf0A = cf[idxA];  cf0B = cf[idxB];
        spline_solve(yy, b, r1 % CC, y, Mv);
        horner_coefs(y, Mv, cf);
        cf1A = cf[idxA];  cf1B = cf[idxB];
    }

    float fp0[EPT], fp1[EPT];
    fp0[0] = a00.x; fp0[1] = a00.y; fp0[2] = a00.z; fp0[3] = a00.w;
    fp0[4] = a01.x; fp0[5] = a01.y; fp0[6] = a01.z; fp0[7] = a01.w;
    fp1[0] = a10.x; fp1[1] = a10.y; fp1[2] = a10.z; fp1[3] = a10.w;
    fp1[4] = a11.x; fp1[5] = a11.y; fp1[6] = a11.z; fp1[7] = a11.w;

    // ---- curve + thread-local inclusive scan, both rows interleaved ----
    float lc0[EPT], lc1[EPT];
    float run0 = 0.0f, run1 = 0.0f;
    #pragma unroll
    for (int k = 0; k < EPT; ++k) {
        float ft = (float)(t0 + k);
        bool inB = ft >= tb;
        float xl = inB ? xlB : xlA;
        float s  = ft - xl;
        f4 c0 = inB ? cf0B : cf0A;
        f4 c1 = inB ? cf1B : cf1A;
        run0 += fmaf(s, fmaf(s, fmaf(s, c0.w, c0.z), c0.y), c0.x);
        run1 += fmaf(s, fmaf(s, fmaf(s, c1.w, c1.z), c1.y), c1.x);
        lc0[k] = run0;
        lc1[k] = run1;
    }
    // curve at t0+EPT (for the lane-63 boundary reconstruction)
    float cN0, cN1;
    {
        float ft = (float)(t0 + EPT);
        bool inB = ft >= tb;
        float xl = inB ? xlB : xlA;
        float s  = ft - xl;
        f4 c0 = inB ? cf0B : cf0A;
        f4 c1 = inB ? cf1B : cf1A;
        cN0 = fmaf(s, fmaf(s, fmaf(s, c0.w, c0.z), c0.y), c0.x);
        cN1 = fmaf(s, fmaf(s, fmaf(s, c1.w, c1.z), c1.y), c1.x);
    }

    // ---- wave scan (shfl, dual) + cross-wave fixup (barrier 1) ----
    const int lane = tid & 63, wid = tid >> 6;
    float w0 = run0, w1 = run1;
    #pragma unroll
    for (int d = 1; d < 64; d <<= 1) {
        float v0 = __shfl_up(w0, d, 64);
        float v1 = __shfl_up(w1, d, 64);
        if (lane >= d) { w0 += v0; w1 += v1; }
    }
    if (lane == 63) { sh_w0[wid] = w0; sh_w1[wid] = w1; }
    __syncthreads();                            // B1
    float wo0 = 0.0f, tt0 = 0.0f, wo1 = 0.0f, tt1 = 0.0f;
    #pragma unroll
    for (int w = 0; w < NWAVE; ++w) {           // ascending: order matters for
        float s0 = sh_w0[w], s1 = sh_w1[w];     // the lane-63 bit-exact proof
        tt0 += s0;  tt1 += s1;
        if (w < wid) { wo0 += s0; wo1 += s1; }
    }
    const float of0 = wo0 + (w0 - run0);        // exclusive prefix
    const float of1 = wo1 + (w1 - run1);
    const float sc0 = 4095.0f / tt0;
    const float sc1 = 4095.0f / tt1;

    float xp0[EPT + 1], xp1[EPT + 1];
    #pragma unroll
    for (int k = 0; k < EPT; ++k) {
        xp0[k] = (lc0[k] + of0) * sc0;
        xp1[k] = (lc1[k] + of1) * sc1;
    }
    // Boundary xp[EPT] without a barrier:
    //  lanes 0..62: shfl_down of neighbor's xp[0] -> exact bits.
    //  lane 63: ((wo + w) + cN) * sc. Neighbor (lane 0, wave wid+1) computes
    //    (lc[0] + of)*sc with lc[0] = 0+cN = cN, of = wo' + (w-run = +0) = wo',
    //    and wo' = ascending sum over w<=wid = wo (+) w  -> commutative-equal,
    //    so both expressions are bit-identical. Coverage stays gap-free.
    {
        float n0 = __shfl_down(xp0[0], 1, 64);
        float n1 = __shfl_down(xp1[0], 1, 64);
        float l0 = ((wo0 + w0) + cN0) * sc0;
        float l1 = ((wo1 + w1) + cN1) * sc1;
        xp0[EPT] = (lane == 63) ? l0 : n0;      // tid NTHR-1: unused
        xp1[EPT] = (lane == 63) ? l1 : n1;
    }

    // ---- direct forward scatter of final values, row 0 then row 1 ----
    // segment j owns q in [ceil(xp[j]), ceil(xp[j+1])-1]
    #pragma unroll
    for (int k = 0; k < EPT; ++k) {
        const int seg = t0 + k;
        if (seg < TT - 1) {
            float xa = xp0[k], xb = xp0[k + 1];
            float fa = fp0[k];
            float fb = (k < EPT - 1) ? fp0[k + 1] : fpb0;
            float d  = xb - xa;
            float slope = (d > 0.0f) ? (fb - fa) * __builtin_amdgcn_rcpf(d) : 0.0f;
            float a0 = fmaf(-xa, slope, fa);
            int qlo = (int)ceilf(xa);  if (qlo < 0) qlo = 0;
            int qhi = (int)ceilf(xb);  if (qhi > TT) qhi = TT;
            for (int q = qlo; q < qhi; ++q)
                sh_res0[padi(q)] = fmaf((float)q, slope, a0);
        }
    }
    #pragma unroll
    for (int k = 0; k < EPT; ++k) {
        const int seg = t0 + k;
        if (seg < TT - 1) {
            float xa = xp1[k], xb = xp1[k + 1];
            float fa = fp1[k];
            float fb = (k < EPT - 1) ? fp1[k + 1] : fpb1;
            float d  = xb - xa;
            float slope = (d > 0.0f) ? (fb - fa) * __builtin_amdgcn_rcpf(d) : 0.0f;
            float a0 = fmaf(-xa, slope, fa);
            int qlo = (int)ceilf(xa);  if (qlo < 0) qlo = 0;
            int qhi = (int)ceilf(xb);  if (qhi > TT) qhi = TT;
            for (int q = qlo; q < qhi; ++q)
                sh_res1[padi(q)] = fmaf((float)q, slope, a0);
        }
    }
    if (tid == 0) {                             // heads: q < xp[0] -> fp[0]
        int q1 = (int)ceilf(xp0[0]);  if (q1 > TT) q1 = TT;
        for (int q = 0; q < q1; ++q) sh_res0[padi(q)] = fp0[0];
        q1 = (int)ceilf(xp1[0]);  if (q1 > TT) q1 = TT;
        for (int q = 0; q < q1; ++q) sh_res1[padi(q)] = fp1[0];
    }
    if (tid == NTHR - 1) {                      // tails: q >= xp[4095] -> fp[4095]
        int q0 = (int)ceilf(xp0[EPT - 1]);  if (q0 < 0) q0 = 0;
        for (int q = q0; q < TT; ++q) sh_res0[padi(q)] = fp0[EPT - 1];
        q0 = (int)ceilf(xp1[EPT - 1]);  if (q0 < 0) q0 = 0;
        for (int q = q0; q < TT; ++q) sh_res1[padi(q)] = fp1[EPT - 1];
    }
    __syncthreads();                            // B2: both sh_res complete

    // ---- restage: coalesced nontemporal float4 stores, both rows ----
    #pragma unroll
    for (int kk = 0; kk < 2; ++kk) {
        int i4  = tid + NTHR * kk;
        int fb4 = 4 * i4;
        int p   = padi(fb4);
        f4 v0, v1;
        v0.x = sh_res0[p + 0];  v0.y = sh_res0[p + 1];
        v0.z = sh_res0[p + 2];  v0.w = sh_res0[p + 3];
        v1.x = sh_res1[p + 0];  v1.y = sh_res1[p + 1];
        v1.z = sh_res1[p + 2];  v1.w = sh_res1[p + 3];
        nt_store4(or0 + fb4, v0);
        nt_store4(or1 + fb4, v1);
    }
}

extern "C" void kernel_launch(void* const* d_in, const int* in_sizes, int n_in,
                              void* d_out, int out_size, void* d_ws, size_t ws_size,
                              hipStream_t stream) {
    const float* x    = (const float*)d_in[0];   // (64,128,4096) fp32
    const float* yy   = (const float*)d_in[1];   // (64,6,128)    fp32
    const float* mask = (const float*)d_in[2];   // (64,1,1)      fp32
    float* out = (float*)d_out;                  // (64,128,4096) fp32

    if (d_ws != nullptr && ws_size >= TABBYTES) {
        f4* tab = (f4*)d_ws;
        spline_coef_kernel<<<dim3(NROW / 256), dim3(256), 0, stream>>>(yy, tab);
        timewarp_kernel<1><<<dim3(NROW / 2), dim3(NTHR), 0, stream>>>(x, yy, mask, tab, out);
    } else {
        timewarp_kernel<0><<<dim3(NROW / 2), dim3(NTHR), 0, stream>>>(x, yy, mask, nullptr, out);
    }
}